// Round 12
// baseline (1274.663 us; speedup 1.0000x reference)
//
#include <hip/hip_runtime.h>

// Problem constants (fixed by reference file)
#define NN 50000
#define EE 800000
#define BG 50

typedef unsigned short ushort_t;
typedef __bf16 bf16x8 __attribute__((ext_vector_type(8)));
typedef float f32x4 __attribute__((ext_vector_type(4)));

// ---------- bf16 helpers (raw ushort storage; RNE rounding) ----------
__device__ __forceinline__ float b2f(ushort_t h) {
    unsigned int u = ((unsigned int)h) << 16;
    float f; __builtin_memcpy(&f, &u, 4); return f;
}
__device__ __forceinline__ ushort_t f2b(float f) {
    unsigned int u; __builtin_memcpy(&u, &f, 4);
    unsigned int r = u + 0x7fffu + ((u >> 16) & 1u);
    return (ushort_t)(r >> 16);
}

// async global->LDS, 16B per lane; LDS dest is wave-uniform base (+lane*16 implicit)
__device__ __forceinline__ void async_ld16(const void* g, void* l) {
    __builtin_amdgcn_global_load_lds(
        (__attribute__((address_space(1))) unsigned int*)(void*)g,
        (__attribute__((address_space(3))) unsigned int*)l, 16, 0, 0);
}

// ---------- input dtype detector: 1 = bf16 array, 0 = fp32 array ----------
__global__ void k_detect(const ushort_t* xs, int* flag) {
    __shared__ int cnt;
    if (threadIdx.x == 0) cnt = 0;
    __syncthreads();
    int e = (xs[2 * threadIdx.x] >> 7) & 0xFF;
    if (e >= 96 && e <= 142) atomicAdd(&cnt, 1);
    __syncthreads();
    if (threadIdx.x == 0) *flag = (cnt >= 300) ? 1 : 0;
}

// ---------- batched cast of all 25 float tensors to bf16 ws scratch ----------
// Also zeroes degi (first NN threads) so no separate memset dispatch is needed.
struct CastJobs {
    const void* src[25];
    int off[25];     // dst element offset from ws base
    int start[26];   // exclusive prefix of sizes
};
__global__ void k_castall(CastJobs jb, ushort_t* base, const int* flag, int total,
                          int* degi) {
    int i = blockIdx.x * 256 + threadIdx.x;
    if (i < NN) degi[i] = 0;
    if (i >= total) return;
    int lo = 0;
    while (i >= jb.start[lo + 1]) ++lo;   // <=25 iters; block-uniform mostly
    int k = i - jb.start[lo];
    const void* s = jb.src[lo];
    ushort_t v;
    if (*flag) v = ((const ushort_t*)s)[k];
    else       v = f2b(((const float*)s)[k]);
    base[jb.off[lo] + k] = v;
}

// ---------- graph prep ----------
__global__ void k_deg(const int* edge, int* degi) {
    int e = blockIdx.x * 256 + threadIdx.x;
    if (e < EE) atomicAdd(&degi[edge[EE + e]], 1);
}
// exclusive scan of degi -> rowptr (3 stages); also computes dinv
__global__ void k_scan1(const int* degi, int* rowptr, int* bsum, float* dinv) {
    __shared__ int sh[1024];
    int t = threadIdx.x, i = blockIdx.x * 1024 + t;
    int v = (i < NN) ? degi[i] : 0;
    if (i < NN) dinv[i] = v > 0 ? rsqrtf((float)v) : 0.0f;
    sh[t] = v; __syncthreads();
    for (int off = 1; off < 1024; off <<= 1) {
        int add = (t >= off) ? sh[t - off] : 0;
        __syncthreads();
        sh[t] += add;
        __syncthreads();
    }
    if (i < NN) rowptr[i] = sh[t] - v;          // exclusive, block-local
    if (t == 1023) bsum[blockIdx.x] = sh[t];
}
// block-offset fixup + per-graph counts & start indices (batch sorted)
__global__ void k_scan2(const int* bsum, int* boff, int* rowptr,
                        const int* batch, float* cntf, int* gstart) {
    int t = threadIdx.x;
    if (t == 0) {
        int run = 0;
        for (int j = 0; j < 49; ++j) { boff[j] = run; run += bsum[j]; }
        rowptr[NN] = run;   // == EE
        gstart[BG] = NN;
    }
    if (t < BG) {
        int g = t;
        int lo = 0, hi = NN;
        while (lo < hi) { int m = (lo + hi) >> 1; if (batch[m] < g) lo = m + 1; else hi = m; }
        int a = lo; lo = 0; hi = NN;
        while (lo < hi) { int m = (lo + hi) >> 1; if (batch[m] < g + 1) lo = m + 1; else hi = m; }
        gstart[g] = a;
        cntf[g] = fmaxf((float)(lo - a), 1.0f);
    }
}
// offset fixup; also zeroes cursor for k_fill (no separate memset)
__global__ void k_scan3(int* rowptr, const int* boff, int* cursor) {
    int i = blockIdx.x * 256 + threadIdx.x;
    if (i < NN) { rowptr[i] += boff[i >> 10]; cursor[i] = 0; }
}
// CSR fill; edge metadata packed as int2{src, weight-bits} -> 1 load/edge in prop
__global__ void k_fill(const int* edge, const float* dinv, const int* rowptr,
                       int* cursor, int2* epack) {
    int e = blockIdx.x * 256 + threadIdx.x;
    if (e >= EE) return;
    int s = edge[e], d = edge[EE + e];
    int slot = atomicAdd(&cursor[d], 1);
    int pos = rowptr[d] + slot;
    float wv = -dinv[s] * dinv[d];
    int2 pk; pk.x = s; __builtin_memcpy(&pk.y, &wv, 4);
    epack[pos] = pk;
}

// ---------- batched weight transposes: all 8 (K,C)->(C,K) jobs, 1 dispatch ----
struct TJobs {
    int soff[8], doff[8], K[8], C[8];
    int tstart[9];   // exclusive prefix of 32x32-tile counts
};
__global__ void k_transposeAll(TJobs tj, const ushort_t* Wst, ushort_t* WTall) {
    __shared__ ushort_t tile[32][33];
    int b = blockIdx.x;
    int j = 0;
    while (b >= tj.tstart[j + 1]) ++j;
    int t = b - tj.tstart[j];
    int K = tj.K[j], C = tj.C[j];
    int tilesX = K >> 5;
    int bx = (t % tilesX) * 32, by = (t / tilesX) * 32;
    const ushort_t* W = Wst + tj.soff[j];
    ushort_t* WT = WTall + tj.doff[j];
    int tx = threadIdx.x, ty = threadIdx.y;   // block (32,8)
    for (int i = ty; i < 32; i += 8) tile[i][tx] = W[(size_t)(bx + i) * C + by + tx];
    __syncthreads();
    for (int i = ty; i < 32; i += 8) WT[(size_t)(by + i) * K + bx + tx] = tile[tx][i];
}

// ---------- unified CSR prop, wave-per-node (r10 form: 4x/1x cascade) ----------
// SL lanes per edge (C = SL*8 channels, 16B gathers), EG = 64/SL edges per issue.
// out[n,c] = alpha*sum_j w_j*src[s_j,c] + addP[n,c] - subP[n,c] + bias[c]
template<int SL>
__launch_bounds__(256)
__global__ void k_prop3(ushort_t* out, int ldo,
                        const ushort_t* src, int lds_, int soff,
                        const ushort_t* addP, int lda_, int aoff,
                        const ushort_t* subP, int ldsu, int suoff,
                        const ushort_t* bias, float alpha,
                        const int* rowptr, const int2* epack) {
    constexpr int EG = 64 / SL;
    int n = blockIdx.x * 4 + (threadIdx.x >> 6);
    if (n >= NN) return;
    int lane = threadIdx.x & 63;
    int eg = lane / SL;                 // which edge within the group
    int cpos = (lane % SL) * 8;         // 8 channels per lane
    int r0 = rowptr[n], r1 = rowptr[n + 1];
    float acc[8];
#pragma unroll
    for (int i = 0; i < 8; ++i) acc[i] = 0.f;
    const ushort_t* sbase = src + soff + cpos;
    int j = r0 + eg;
    for (; j + 3 * EG < r1; j += 4 * EG) {
        int2 p[4];
#pragma unroll
        for (int u = 0; u < 4; ++u) p[u] = epack[j + u * EG];
        __bf16 v[4][8];
#pragma unroll
        for (int u = 0; u < 4; ++u)
            __builtin_memcpy(v[u], sbase + (size_t)p[u].x * lds_, 16);
#pragma unroll
        for (int u = 0; u < 4; ++u) {
            float wv; __builtin_memcpy(&wv, &p[u].y, 4);
#pragma unroll
            for (int i = 0; i < 8; ++i) acc[i] += wv * (float)v[u][i];
        }
    }
    for (; j < r1; j += EG) {
        int2 p0 = epack[j];
        float wv; __builtin_memcpy(&wv, &p0.y, 4);
        __bf16 v0[8];
        __builtin_memcpy(v0, sbase + (size_t)p0.x * lds_, 16);
#pragma unroll
        for (int i = 0; i < 8; ++i) acc[i] += wv * (float)v0[i];
    }
    // merge edge-group partials (lanes differing in high bits >= SL)
#pragma unroll
    for (int off = SL; off < 64; off <<= 1)
#pragma unroll
        for (int i = 0; i < 8; ++i) acc[i] += __shfl_xor(acc[i], off);

    if (eg == 0) {
        float res[8];
#pragma unroll
        for (int i = 0; i < 8; ++i) res[i] = alpha * acc[i];
        if (addP) {
            __bf16 a[8];
            __builtin_memcpy(a, addP + (size_t)n * lda_ + aoff + cpos, 16);
#pragma unroll
            for (int i = 0; i < 8; ++i) res[i] += (float)a[i];
        }
        if (subP) {
            __bf16 sm[8];
            __builtin_memcpy(sm, subP + (size_t)n * ldsu + suoff + cpos, 16);
#pragma unroll
            for (int i = 0; i < 8; ++i) res[i] -= (float)sm[i];
        }
        if (bias) {
            __bf16 bb[8];
            __builtin_memcpy(bb, bias + cpos, 16);
#pragma unroll
            for (int i = 0; i < 8; ++i) res[i] += (float)bb[i];
        }
        ushort_t o[8];
#pragma unroll
        for (int i = 0; i < 8; ++i) o[i] = f2b(res[i]);
        __builtin_memcpy(out + (size_t)n * ldo + cpos, o, 16);
    }
}

// ---------- GEMM: out(M,N) = [A0|A1|A2](M,Ktot) @ WT^T + bias? ----------
// XOR-swizzled LDS (conflict-free, r7), NT=1 tile (r8 occupancy: 80 VGPR, 24%).
// 1-D grid with XCD-grouping swizzle (r10: FETCH 155->45MB, 75->69us).
__launch_bounds__(256)
__global__ void k_gemm(const ushort_t* A0, const ushort_t* A1, const ushort_t* A2,
                       int lda, const ushort_t* WT, const ushort_t* bias, int hasBias,
                       ushort_t* out, int ldout, int Ktot, int NX, int MT) {
    __shared__ __align__(16) ushort_t ldsA[128 * 64];
    __shared__ __align__(16) ushort_t ldsB[128 * 64];
    const int lin = blockIdx.x;
    const int x7 = lin & 7, rr = lin >> 3;
    const int n_t = rr % NX, mhi = rr / NX;
    const int m_t = mhi * 8 + x7;
    if (m_t >= MT) return;
    const int tid = threadIdx.x, lane = tid & 63, w = tid >> 6;
    const int wm = w & 1, wn = w >> 1;
    const int m0 = m_t * 128, n0 = n_t * 128;
    const int KT = Ktot / 64, per = lda >> 6;

    f32x4 acc[4][4];
#pragma unroll
    for (int i = 0; i < 4; ++i)
#pragma unroll
        for (int j = 0; j < 4; ++j) acc[i][j] = (f32x4){0.f, 0.f, 0.f, 0.f};

    const int srow = lane >> 3;
    const int scolX = (((lane & 7) ^ srow) << 3);   // swizzled source column
    const int l7 = lane & 7;                        // == fragment row & 7

    for (int kt = 0; kt < KT; ++kt) {
        int seg = kt / per, lk = (kt - seg * per) * 64;
        const ushort_t* Ap = (seg == 0) ? A0 : ((seg == 1) ? A1 : A2);
        __syncthreads();   // LDS from previous iter fully consumed
#pragma unroll
        for (int t = 0; t < 4; ++t) {
            int inst = (w << 2) + t;
            int row = inst * 8 + srow;
            int gr = m0 + row; if (gr >= NN) gr = NN - 1;            // clamp M tail
            async_ld16(Ap + (size_t)gr * lda + lk + scolX, &ldsA[inst * 512]);
            async_ld16(WT + (size_t)(n0 + row) * Ktot + kt * 64 + scolX, &ldsB[inst * 512]);
        }
        __builtin_amdgcn_s_waitcnt(0);
        __syncthreads();
#pragma unroll
        for (int kk = 0; kk < 64; kk += 32) {
            bf16x8 aF[4], bF[4];
            int qx = ((((kk >> 3) + (lane >> 4)) ^ l7) << 3);   // swizzled read column
#pragma unroll
            for (int i = 0; i < 4; ++i) {
                aF[i] = *(const bf16x8*)&ldsA[(wm * 64 + i * 16 + (lane & 15)) * 64 + qx];
                bF[i] = *(const bf16x8*)&ldsB[(wn * 64 + i * 16 + (lane & 15)) * 64 + qx];
            }
#pragma unroll
            for (int i = 0; i < 4; ++i)
#pragma unroll
                for (int j = 0; j < 4; ++j)
                    acc[i][j] = __builtin_amdgcn_mfma_f32_16x16x32_bf16(aF[i], bF[j], acc[i][j], 0, 0, 0);
        }
    }
    // epilogue: C/D layout col=lane&15, row=(lane>>4)*4+reg  [m89/m91]
#pragma unroll
    for (int i = 0; i < 4; ++i) {
        int rbase = m0 + wm * 64 + i * 16 + ((lane >> 4) << 2);
#pragma unroll
        for (int j = 0; j < 4; ++j) {
            int col = n0 + wn * 64 + j * 16 + (lane & 15);
            float bv = hasBias ? b2f(bias[col]) : 0.0f;
#pragma unroll
            for (int r = 0; r < 4; ++r) {
                int row = rbase + r;
                if (row < NN) out[(size_t)row * ldout + col] = f2b(acc[i][j][r] + bv);
            }
        }
    }
}

// ---------- per-graph sum/sumsq: block g = graph g, no atomics, no memset ------
// 4 waves split graph g's node range [gstart[g], gstart[g+1]); lane owns VEC
// channels; LDS reduce across waves; wave 0 writes results directly.
template<int VEC>
__launch_bounds__(256)
__global__ void k_stats3(const ushort_t* h, const int* gstart,
                         float* sums, float* sumsq, int withSq) {
    constexpr int C = VEC * 64;
    __shared__ float ls[4][C], lq[4][C];
    int g = blockIdx.x;
    int gs = gstart[g], ge = gstart[g + 1];
    int wave = threadIdx.x >> 6, lane = threadIdx.x & 63;
    int coff = lane * VEC;
    float s[VEC], sq[VEC];
#pragma unroll
    for (int i = 0; i < VEC; ++i) { s[i] = 0.f; sq[i] = 0.f; }
    for (int n = gs + wave; n < ge; n += 4) {
        __bf16 v[VEC];
        __builtin_memcpy(v, h + (size_t)n * C + coff, VEC * 2);
#pragma unroll
        for (int i = 0; i < VEC; ++i) {
            float f = (float)v[i];
            s[i] += f; sq[i] += f * f;
        }
    }
#pragma unroll
    for (int i = 0; i < VEC; ++i) { ls[wave][coff + i] = s[i]; lq[wave][coff + i] = sq[i]; }
    __syncthreads();
    if (wave == 0) {
#pragma unroll
        for (int i = 0; i < VEC; ++i) {
            int c = coff + i;
            float ts = ls[0][c] + ls[1][c] + ls[2][c] + ls[3][c];
            sums[g * C + c] = ts;
            if (withSq) {
                float tq = lq[0][c] + lq[1][c] + lq[2][c] + lq[3][c];
                sumsq[g * C + c] = tq;
            }
        }
    }
}

// ---------- GraphNorm + leaky ReLU (+ residual on last layer), wave-per-node ----
template<int VEC>
__launch_bounds__(256)
__global__ void k_norm2(const ushort_t* hpre, const int* batch, const float* sums,
                        const float* sumsq, const float* cntf,
                        const ushort_t* gw, const ushort_t* gb, const ushort_t* gms,
                        const ushort_t* xres, ushort_t* out, int addres) {
    constexpr int C = VEC * 64;
    int n = blockIdx.x * 4 + (threadIdx.x >> 6);
    if (n >= NN) return;
    int lane = threadIdx.x & 63;
    int coff = lane * VEC;
    int g = batch[n];
    float cg = cntf[g];
    float sm[VEC], sq[VEC];
    __builtin_memcpy(sm, sums  + g * C + coff, VEC * 4);
    __builtin_memcpy(sq, sumsq + g * C + coff, VEC * 4);
    __bf16 vgw[VEC], vgb[VEC], vms[VEC], vh[VEC];
    __builtin_memcpy(vgw, gw + coff, VEC * 2);
    __builtin_memcpy(vgb, gb + coff, VEC * 2);
    __builtin_memcpy(vms, gms + coff, VEC * 2);
    __builtin_memcpy(vh, hpre + (size_t)n * C + coff, VEC * 2);
    __bf16 vx[VEC];
    if (addres) __builtin_memcpy(vx, xres + (size_t)n * 128 + coff, VEC * 2);
    ushort_t o[VEC];
#pragma unroll
    for (int i = 0; i < VEC; ++i) {
        float mean = sm[i] / cg;
        float ms = (float)vms[i];
        float var = sq[i] / cg - mean * mean * ms * (2.0f - ms);
        var = fmaxf(var, 0.0f);
        float y = (float)vgw[i] * ((float)vh[i] - ms * mean) * rsqrtf(var + 1e-5f) + (float)vgb[i];
        y = (y >= 0.0f) ? y : 0.2f * y;
        if (addres) y += (float)vx[i];
        o[i] = f2b(y);
    }
    __builtin_memcpy(out + (size_t)n * C + coff, o, VEC * 2);
}

// ---------- head: out = tanh(pooled/cnt @ W1 + b1) @ W2 + b2 ----------
__global__ void k_head(const float* pooled, const float* cntf,
                       const ushort_t* W1, const ushort_t* b1,
                       const ushort_t* W2, const ushort_t* b2s, void* out,
                       const int* flag) {
    __shared__ float pl[128];
    __shared__ float hid[64];
    int g = blockIdx.x, t = threadIdx.x;   // 64 threads
    float inv = 1.0f / cntf[g];
    for (int k = t; k < 128; k += 64) pl[k] = pooled[g * 128 + k] * inv;
    __syncthreads();
    float a = b2f(b1[t]);
    for (int k = 0; k < 128; ++k) a += pl[k] * b2f(W1[k * 64 + t]);
    hid[t] = tanhf(a);
    __syncthreads();
    if (t < 10) {
        float o = b2f(b2s[t]);
        for (int j = 0; j < 64; ++j) o += hid[j] * b2f(W2[j * 10 + t]);
        if (*flag) ((ushort_t*)out)[g * 10 + t] = f2b(o);
        else       ((float*)out)[g * 10 + t]    = o;
    }
}

extern "C" void kernel_launch(void* const* d_in, const int* in_sizes, int n_in,
                              void* d_out, int out_size, void* d_ws, size_t ws_size,
                              hipStream_t stream) {
    (void)in_sizes; (void)n_in; (void)out_size; (void)ws_size;

    const void* x_raw = d_in[0];
    const int* edge   = (const int*)d_in[1];
    const int* batch  = (const int*)d_in[2];

    // ---- workspace layout (256B-aligned; total 228,991,488 B ≈ 229 MB) ----
    char* ws = (char*)d_ws;
    float*    dinv   = (float*)   (ws + 0);           //   200,000 B
    int*      degi   = (int*)     (ws + 200192);      //   200,000 B
    int*      rowptr = (int*)     (ws + 400384);      //   200,004 B
    int*      cursor = (int*)     (ws + 600576);      //   200,000 B
    int*      bsum   = (int*)     (ws + 800768);      //       196 B
    int*      boff   = (int*)     (ws + 801024);      //       196 B
    float*    cntf   = (float*)   (ws + 801280);      //       200 B
    int*      dflag  = (int*)     (ws + 801488);      //         4 B
    int*      gstart = (int*)     (ws + 801536);      //       204 B
    float*    sums   = (float*)   (ws + 801792);      //   102,400 B
    float*    sumsq  = (float*)   (ws + 904192);      //   102,400 B
    float*    pooled = (float*)   (ws + 1006592);     //    25,600 B -> 1,032,192
    ushort_t* Xb     = (ushort_t*)(ws + 1032192);     // 12,800,000 B  x staged bf16
    ushort_t* Wst    = (ushort_t*)(ws + 13832192);    //  1,966,080 B  conv W staged
    ushort_t* WTall  = (ushort_t*)(ws + 15798272);    //  1,966,080 B  conv W packed
    ushort_t* SB     = (ushort_t*)(ws + 17764352);    //     27,028 B  small tensors staged
    int2*     epack  = (int2*)    (ws + 17791488);    //  6,400,000 B  packed CSR (src,w)
    ushort_t* T1     = (ushort_t*)(ws + 24191488);    // 51,200,000 B  (T1+T2 contiguous = G region)
    ushort_t* T2     = (ushort_t*)(ws + 75391488);    // 51,200,000 B
    ushort_t* P      = (ushort_t*)(ws + 126591488);   // 51,200,000 B
    ushort_t* HA     = (ushort_t*)(ws + 177791488);   // 51,200,000 B -> end 228,991,488

    const int cins[4]  = {128, 256, 512, 256};
    const int couts[4] = {256, 512, 256, 128};
    const size_t wtoff[4] = {0, 98304, 491520, 884736};  // elem offsets (Wst & WTall)
    // SB element offsets
    const int bo[4] = {0, 256, 768, 1024};
    const int gwo = 1152, gbo = 2304, gmo = 3456;
    const int l1Wo = 4608, l1bo = 12800, l2Wo = 12864, l2bo = 13504;

    const int XB_E = 1032192 / 2, WST_E = 13832192 / 2, SB_E = 17764352 / 2;

    // ---- batched cast jobs ----
    CastJobs jb;
    int sizes[25]; int nj = 0;
    auto addjob = [&](const void* s, int off, int n) {
        jb.src[nj] = s; jb.off[nj] = off; sizes[nj] = n; ++nj;
    };
    addjob(x_raw, XB_E, NN * 128);
    for (int l = 0; l < 4; ++l) {
        addjob(d_in[3 + 5 * l], WST_E + (int)wtoff[l], 3 * cins[l] * couts[l]);
        addjob(d_in[4 + 5 * l], SB_E + bo[l],        couts[l]);
        addjob(d_in[5 + 5 * l], SB_E + gwo + bo[l],  couts[l]);
        addjob(d_in[6 + 5 * l], SB_E + gbo + bo[l],  couts[l]);
        addjob(d_in[7 + 5 * l], SB_E + gmo + bo[l],  couts[l]);
    }
    addjob(d_in[23], SB_E + l1Wo, 128 * 64);
    addjob(d_in[24], SB_E + l1bo, 64);
    addjob(d_in[25], SB_E + l2Wo, 64 * 10);
    addjob(d_in[26], SB_E + l2bo, 10);
    int run = 0;
    for (int k = 0; k < 25; ++k) { jb.start[k] = run; run += sizes[k]; }
    jb.start[25] = run;

    // ---- batched transpose jobs (8 jobs, 32x32 tiles) ----
    TJobs tj;
    int tn = 0, trun = 0;
    auto addt = [&](int soff, int doff, int K, int C) {
        tj.soff[tn] = soff; tj.doff[tn] = doff; tj.K[tn] = K; tj.C[tn] = C;
        tj.tstart[tn] = trun; trun += (K / 32) * (C / 32); ++tn;
    };
    addt((int)wtoff[0], (int)wtoff[0], 3 * cins[0], couts[0]);           // l0: 384x256
    addt((int)wtoff[1], (int)wtoff[1], 3 * cins[1], couts[1]);           // l1: 768x512
    for (int l = 2; l < 4; ++l)
        for (int j2 = 0; j2 < 3; ++j2) {
            int o = (int)wtoff[l] + j2 * cins[l] * couts[l];
            addt(o, o, cins[l], couts[l]);                               // per-j cinxcout
        }
    tj.tstart[8] = trun;   // 960 tiles

    // dtype detect; castall zeroes degi; scan3 zeroes cursor (no memsets)
    k_detect<<<1, 512, 0, stream>>>((const ushort_t*)x_raw, dflag);
    k_castall<<<(run + 255) / 256, 256, 0, stream>>>(jb, (ushort_t*)ws, dflag, run, degi);

    // graph prep
    k_deg<<<(EE + 255) / 256, 256, 0, stream>>>(edge, degi);
    k_scan1<<<49, 1024, 0, stream>>>(degi, rowptr, bsum, dinv);
    k_scan2<<<1, 64, 0, stream>>>(bsum, boff, rowptr, batch, cntf, gstart);
    k_scan3<<<(NN + 255) / 256, 256, 0, stream>>>(rowptr, boff, cursor);
    k_fill<<<(EE + 255) / 256, 256, 0, stream>>>(edge, dinv, rowptr, cursor, epack);

    // weight packing (all 8 transposes, one dispatch)
    k_transposeAll<<<trun, dim3(32, 8), 0, stream>>>(tj, Wst, WTall);

    const int NB = (NN + 3) / 4;
    const int MT = (NN + 127) / 128;          // 391 M-tiles
    const int MG = (MT + 7) / 8;              // 49 groups of 8
    auto prop = [&](int C, ushort_t* o, int ldo,
                    const ushort_t* s, int lds_, int soff,
                    const ushort_t* aP, int lda_, int aoff,
                    const ushort_t* sP, int ldsu, int suoff,
                    const ushort_t* bias, float alpha) {
        if (C == 128)
            k_prop3<16><<<NB, 256, 0, stream>>>(o, ldo, s, lds_, soff, aP, lda_, aoff,
                                                sP, ldsu, suoff, bias, alpha, rowptr, epack);
        else
            k_prop3<32><<<NB, 256, 0, stream>>>(o, ldo, s, lds_, soff, aP, lda_, aoff,
                                                sP, ldsu, suoff, bias, alpha, rowptr, epack);
    };
    auto gemm = [&](const ushort_t* A0, const ushort_t* A1, const ushort_t* A2,
                    int lda, const ushort_t* WT, const ushort_t* bias, int hasBias,
                    ushort_t* o, int ldout, int Ktot, int NX) {
        k_gemm<<<MG * 8 * NX, 256, 0, stream>>>(A0, A1, A2, lda, WT, bias, hasBias,
                                                o, ldout, Ktot, NX, MT);
    };
    auto stats = [&](int C, const ushort_t* h, float* sm, float* sq, int withSq) {
        if (C == 128)      k_stats3<2><<<BG, 256, 0, stream>>>(h, gstart, sm, sq, withSq);
        else if (C == 256) k_stats3<4><<<BG, 256, 0, stream>>>(h, gstart, sm, sq, withSq);
        else               k_stats3<8><<<BG, 256, 0, stream>>>(h, gstart, sm, sq, withSq);
    };
    auto norm = [&](int C, const ushort_t* hp, const ushort_t* gwp, const ushort_t* gbp,
                    const ushort_t* gmp, ushort_t* o, int addres) {
        if (C == 128)      k_norm2<2><<<NB, 256, 0, stream>>>(hp, batch, sums, sumsq, cntf, gwp, gbp, gmp, Xb, o, addres);
        else if (C == 256) k_norm2<4><<<NB, 256, 0, stream>>>(hp, batch, sums, sumsq, cntf, gwp, gbp, gmp, Xb, o, addres);
        else               k_norm2<8><<<NB, 256, 0, stream>>>(hp, batch, sums, sumsq, cntf, gwp, gbp, gmp, Xb, o, addres);
    };

    ushort_t* G = T1;   // mode-B GEMM output (M x 3cout), uses T1+T2 contiguous region
    const ushort_t* hin = Xb;
    for (int l = 0; l < 4; ++l) {
        int cin = cins[l], cout = couts[l];
        if (l < 2) {
            // mode A: propagate in cin, then fat-K GEMM
            prop(cin, T1, cin, hin, cin, 0, nullptr, 0, 0, nullptr, 0, 0, nullptr, 1.0f);
            prop(cin, T2, cin, T1, cin, 0, nullptr, 0, 0, hin, cin, 0, nullptr, 2.0f);
            gemm(hin, T1, T2, cin, WTall + wtoff[l], SB + bo[l], 1, P, cout, 3 * cin,
                 cout / 128);
        } else {
            // mode B: GEMM first (G=[xW0|xW1|xW2]), then propagate in cout
            //   V = G1 + 2*prop(G2);  Ppre = prop(V) + G0 - G2 + bias
            gemm(hin, hin, hin, cin, WTall + wtoff[l], nullptr, 0, G, 3 * cout, cin,
                 (3 * cout) / 128);
            ushort_t* V = HA;   // hin (HA) is dead after the GEMM above
            prop(cout, V, cout, G, 3 * cout, 2 * cout, G, 3 * cout, cout,
                 nullptr, 0, 0, nullptr, 2.0f);
            prop(cout, P, cout, V, cout, 0, G, 3 * cout, 0,
                 G, 3 * cout, 2 * cout, SB + bo[l], 1.0f);
        }
        stats(cout, P, sums, sumsq, 1);
        norm(cout, P, SB + gwo + bo[l], SB + gbo + bo[l], SB + gmo + bo[l], HA, l == 3);
        hin = HA;
    }
    // mean-pool (sum; divide in head) + head
    stats(128, HA, pooled, pooled, 0);
    k_head<<<BG, 64, 0, stream>>>(pooled, cntf, SB + l1Wo, SB + l1bo, SB + l2Wo, SB + l2bo,
                                  d_out, dflag);
}

// Round 13
// 1035.229 us; speedup vs baseline: 1.2313x; 1.2313x over previous
//
#include <hip/hip_runtime.h>

// Problem constants (fixed by reference file)
#define NN 50000
#define EE 800000
#define BG 50

typedef unsigned short ushort_t;
typedef __bf16 bf16x8 __attribute__((ext_vector_type(8)));
typedef float f32x4 __attribute__((ext_vector_type(4)));

// ---------- bf16 helpers (raw ushort storage; RNE rounding) ----------
__device__ __forceinline__ float b2f(ushort_t h) {
    unsigned int u = ((unsigned int)h) << 16;
    float f; __builtin_memcpy(&f, &u, 4); return f;
}
__device__ __forceinline__ ushort_t f2b(float f) {
    unsigned int u; __builtin_memcpy(&u, &f, 4);
    unsigned int r = u + 0x7fffu + ((u >> 16) & 1u);
    return (ushort_t)(r >> 16);
}

// async global->LDS, 16B per lane; LDS dest is wave-uniform base (+lane*16 implicit)
__device__ __forceinline__ void async_ld16(const void* g, void* l) {
    __builtin_amdgcn_global_load_lds(
        (__attribute__((address_space(1))) unsigned int*)(void*)g,
        (__attribute__((address_space(3))) unsigned int*)l, 16, 0, 0);
}

// ---------- input dtype detector: 1 = bf16 array, 0 = fp32 array ----------
__global__ void k_detect(const ushort_t* xs, int* flag) {
    __shared__ int cnt;
    if (threadIdx.x == 0) cnt = 0;
    __syncthreads();
    int e = (xs[2 * threadIdx.x] >> 7) & 0xFF;
    if (e >= 96 && e <= 142) atomicAdd(&cnt, 1);
    __syncthreads();
    if (threadIdx.x == 0) *flag = (cnt >= 300) ? 1 : 0;
}

// ---------- batched cast of all 25 float tensors to bf16 ws scratch ----------
// Also zeroes degi (first NN threads) so no separate memset dispatch is needed.
struct CastJobs {
    const void* src[25];
    int off[25];     // dst element offset from ws base
    int start[26];   // exclusive prefix of sizes
};
__global__ void k_castall(CastJobs jb, ushort_t* base, const int* flag, int total,
                          int* degi) {
    int i = blockIdx.x * 256 + threadIdx.x;
    if (i < NN) degi[i] = 0;
    if (i >= total) return;
    int lo = 0;
    while (i >= jb.start[lo + 1]) ++lo;   // <=25 iters; block-uniform mostly
    int k = i - jb.start[lo];
    const void* s = jb.src[lo];
    ushort_t v;
    if (*flag) v = ((const ushort_t*)s)[k];
    else       v = f2b(((const float*)s)[k]);
    base[jb.off[lo] + k] = v;
}

// ---------- graph prep ----------
__global__ void k_deg(const int* edge, int* degi) {
    int e = blockIdx.x * 256 + threadIdx.x;
    if (e < EE) atomicAdd(&degi[edge[EE + e]], 1);
}
// exclusive scan of degi -> rowptr (3 stages); also computes dinv
__global__ void k_scan1(const int* degi, int* rowptr, int* bsum, float* dinv) {
    __shared__ int sh[1024];
    int t = threadIdx.x, i = blockIdx.x * 1024 + t;
    int v = (i < NN) ? degi[i] : 0;
    if (i < NN) dinv[i] = v > 0 ? rsqrtf((float)v) : 0.0f;
    sh[t] = v; __syncthreads();
    for (int off = 1; off < 1024; off <<= 1) {
        int add = (t >= off) ? sh[t - off] : 0;
        __syncthreads();
        sh[t] += add;
        __syncthreads();
    }
    if (i < NN) rowptr[i] = sh[t] - v;          // exclusive, block-local
    if (t == 1023) bsum[blockIdx.x] = sh[t];
}
// block-offset fixup + per-graph counts (batch sorted; binary search, no atomics)
__global__ void k_scan2(const int* bsum, int* boff, int* rowptr,
                        const int* batch, float* cntf) {
    int t = threadIdx.x;
    if (t == 0) {
        int run = 0;
        for (int j = 0; j < 49; ++j) { boff[j] = run; run += bsum[j]; }
        rowptr[NN] = run;   // == EE
    }
    if (t < BG) {
        int g = t;
        int lo = 0, hi = NN;
        while (lo < hi) { int m = (lo + hi) >> 1; if (batch[m] < g) lo = m + 1; else hi = m; }
        int a = lo; lo = 0; hi = NN;
        while (lo < hi) { int m = (lo + hi) >> 1; if (batch[m] < g + 1) lo = m + 1; else hi = m; }
        cntf[g] = fmaxf((float)(lo - a), 1.0f);
    }
}
// offset fixup; also zeroes cursor for k_fill (no separate memset)
__global__ void k_scan3(int* rowptr, const int* boff, int* cursor) {
    int i = blockIdx.x * 256 + threadIdx.x;
    if (i < NN) { rowptr[i] += boff[i >> 10]; cursor[i] = 0; }
}
// CSR fill; edge metadata packed as int2{src, weight-bits} -> 1 load/edge in prop
__global__ void k_fill(const int* edge, const float* dinv, const int* rowptr,
                       int* cursor, int2* epack) {
    int e = blockIdx.x * 256 + threadIdx.x;
    if (e >= EE) return;
    int s = edge[e], d = edge[EE + e];
    int slot = atomicAdd(&cursor[d], 1);
    int pos = rowptr[d] + slot;
    float wv = -dinv[s] * dinv[d];
    int2 pk; pk.x = s; __builtin_memcpy(&pk.y, &wv, 4);
    epack[pos] = pk;
}

// ---------- batched weight transposes: all 8 (K,C)->(C,K) jobs, 1 dispatch ----
struct TJobs {
    int soff[8], doff[8], K[8], C[8];
    int tstart[9];   // exclusive prefix of 32x32-tile counts
};
__global__ void k_transposeAll(TJobs tj, const ushort_t* Wst, ushort_t* WTall) {
    __shared__ ushort_t tile[32][33];
    int b = blockIdx.x;
    int j = 0;
    while (b >= tj.tstart[j + 1]) ++j;
    int t = b - tj.tstart[j];
    int K = tj.K[j], C = tj.C[j];
    int tilesX = K >> 5;
    int bx = (t % tilesX) * 32, by = (t / tilesX) * 32;
    const ushort_t* W = Wst + tj.soff[j];
    ushort_t* WT = WTall + tj.doff[j];
    int tx = threadIdx.x, ty = threadIdx.y;   // block (32,8)
    for (int i = ty; i < 32; i += 8) tile[i][tx] = W[(size_t)(bx + i) * C + by + tx];
    __syncthreads();
    for (int i = ty; i < 32; i += 8) WT[(size_t)(by + i) * K + bx + tx] = tile[tx][i];
}

// ---------- unified CSR prop, wave-per-node (r10 form: 4x/1x cascade) ----------
// SL lanes per edge (C = SL*8 channels, 16B gathers), EG = 64/SL edges per issue.
// out[n,c] = alpha*sum_j w_j*src[s_j,c] + addP[n,c] - subP[n,c] + bias[c]
template<int SL>
__launch_bounds__(256)
__global__ void k_prop3(ushort_t* out, int ldo,
                        const ushort_t* src, int lds_, int soff,
                        const ushort_t* addP, int lda_, int aoff,
                        const ushort_t* subP, int ldsu, int suoff,
                        const ushort_t* bias, float alpha,
                        const int* rowptr, const int2* epack) {
    constexpr int EG = 64 / SL;
    int n = blockIdx.x * 4 + (threadIdx.x >> 6);
    if (n >= NN) return;
    int lane = threadIdx.x & 63;
    int eg = lane / SL;                 // which edge within the group
    int cpos = (lane % SL) * 8;         // 8 channels per lane
    int r0 = rowptr[n], r1 = rowptr[n + 1];
    float acc[8];
#pragma unroll
    for (int i = 0; i < 8; ++i) acc[i] = 0.f;
    const ushort_t* sbase = src + soff + cpos;
    int j = r0 + eg;
    for (; j + 3 * EG < r1; j += 4 * EG) {
        int2 p[4];
#pragma unroll
        for (int u = 0; u < 4; ++u) p[u] = epack[j + u * EG];
        __bf16 v[4][8];
#pragma unroll
        for (int u = 0; u < 4; ++u)
            __builtin_memcpy(v[u], sbase + (size_t)p[u].x * lds_, 16);
#pragma unroll
        for (int u = 0; u < 4; ++u) {
            float wv; __builtin_memcpy(&wv, &p[u].y, 4);
#pragma unroll
            for (int i = 0; i < 8; ++i) acc[i] += wv * (float)v[u][i];
        }
    }
    for (; j < r1; j += EG) {
        int2 p0 = epack[j];
        float wv; __builtin_memcpy(&wv, &p0.y, 4);
        __bf16 v0[8];
        __builtin_memcpy(v0, sbase + (size_t)p0.x * lds_, 16);
#pragma unroll
        for (int i = 0; i < 8; ++i) acc[i] += wv * (float)v0[i];
    }
    // merge edge-group partials (lanes differing in high bits >= SL)
#pragma unroll
    for (int off = SL; off < 64; off <<= 1)
#pragma unroll
        for (int i = 0; i < 8; ++i) acc[i] += __shfl_xor(acc[i], off);

    if (eg == 0) {
        float res[8];
#pragma unroll
        for (int i = 0; i < 8; ++i) res[i] = alpha * acc[i];
        if (addP) {
            __bf16 a[8];
            __builtin_memcpy(a, addP + (size_t)n * lda_ + aoff + cpos, 16);
#pragma unroll
            for (int i = 0; i < 8; ++i) res[i] += (float)a[i];
        }
        if (subP) {
            __bf16 sm[8];
            __builtin_memcpy(sm, subP + (size_t)n * ldsu + suoff + cpos, 16);
#pragma unroll
            for (int i = 0; i < 8; ++i) res[i] -= (float)sm[i];
        }
        if (bias) {
            __bf16 bb[8];
            __builtin_memcpy(bb, bias + cpos, 16);
#pragma unroll
            for (int i = 0; i < 8; ++i) res[i] += (float)bb[i];
        }
        ushort_t o[8];
#pragma unroll
        for (int i = 0; i < 8; ++i) o[i] = f2b(res[i]);
        __builtin_memcpy(out + (size_t)n * ldo + cpos, o, 16);
    }
}

// ---------- GEMM: out(M,N) = [A0|A1|A2](M,Ktot) @ WT^T + bias? ----------
// XOR-swizzled LDS (conflict-free, r7), NT=1 tile (r8 occupancy: 80 VGPR, 24%).
// 1-D grid with XCD-grouping swizzle (r10: FETCH 155->45MB, 75->69us).
__launch_bounds__(256)
__global__ void k_gemm(const ushort_t* A0, const ushort_t* A1, const ushort_t* A2,
                       int lda, const ushort_t* WT, const ushort_t* bias, int hasBias,
                       ushort_t* out, int ldout, int Ktot, int NX, int MT) {
    __shared__ __align__(16) ushort_t ldsA[128 * 64];
    __shared__ __align__(16) ushort_t ldsB[128 * 64];
    const int lin = blockIdx.x;
    const int x7 = lin & 7, rr = lin >> 3;
    const int n_t = rr % NX, mhi = rr / NX;
    const int m_t = mhi * 8 + x7;
    if (m_t >= MT) return;
    const int tid = threadIdx.x, lane = tid & 63, w = tid >> 6;
    const int wm = w & 1, wn = w >> 1;
    const int m0 = m_t * 128, n0 = n_t * 128;
    const int KT = Ktot / 64, per = lda >> 6;

    f32x4 acc[4][4];
#pragma unroll
    for (int i = 0; i < 4; ++i)
#pragma unroll
        for (int j = 0; j < 4; ++j) acc[i][j] = (f32x4){0.f, 0.f, 0.f, 0.f};

    const int srow = lane >> 3;
    const int scolX = (((lane & 7) ^ srow) << 3);   // swizzled source column
    const int l7 = lane & 7;                        // == fragment row & 7

    for (int kt = 0; kt < KT; ++kt) {
        int seg = kt / per, lk = (kt - seg * per) * 64;
        const ushort_t* Ap = (seg == 0) ? A0 : ((seg == 1) ? A1 : A2);
        __syncthreads();   // LDS from previous iter fully consumed
#pragma unroll
        for (int t = 0; t < 4; ++t) {
            int inst = (w << 2) + t;
            int row = inst * 8 + srow;
            int gr = m0 + row; if (gr >= NN) gr = NN - 1;            // clamp M tail
            async_ld16(Ap + (size_t)gr * lda + lk + scolX, &ldsA[inst * 512]);
            async_ld16(WT + (size_t)(n0 + row) * Ktot + kt * 64 + scolX, &ldsB[inst * 512]);
        }
        __builtin_amdgcn_s_waitcnt(0);
        __syncthreads();
#pragma unroll
        for (int kk = 0; kk < 64; kk += 32) {
            bf16x8 aF[4], bF[4];
            int qx = ((((kk >> 3) + (lane >> 4)) ^ l7) << 3);   // swizzled read column
#pragma unroll
            for (int i = 0; i < 4; ++i) {
                aF[i] = *(const bf16x8*)&ldsA[(wm * 64 + i * 16 + (lane & 15)) * 64 + qx];
                bF[i] = *(const bf16x8*)&ldsB[(wn * 64 + i * 16 + (lane & 15)) * 64 + qx];
            }
#pragma unroll
            for (int i = 0; i < 4; ++i)
#pragma unroll
                for (int j = 0; j < 4; ++j)
                    acc[i][j] = __builtin_amdgcn_mfma_f32_16x16x32_bf16(aF[i], bF[j], acc[i][j], 0, 0, 0);
        }
    }
    // epilogue: C/D layout col=lane&15, row=(lane>>4)*4+reg  [m89/m91]
#pragma unroll
    for (int i = 0; i < 4; ++i) {
        int rbase = m0 + wm * 64 + i * 16 + ((lane >> 4) << 2);
#pragma unroll
        for (int j = 0; j < 4; ++j) {
            int col = n0 + wn * 64 + j * 16 + (lane & 15);
            float bv = hasBias ? b2f(bias[col]) : 0.0f;
#pragma unroll
            for (int r = 0; r < 4; ++r) {
                int row = rbase + r;
                if (row < NN) out[(size_t)row * ldout + col] = f2b(acc[i][j][r] + bv);
            }
        }
    }
}

// ---------- per-(graph,channel) sum / sumsq, wave-per-32-node-chunk (r10) ------
// VEC channels/lane (16B loads); accumulate locally, flush atomics on graph change
// (batch sorted -> ~1 flush per wave). Distinct addresses per lane -> no contention.
template<int VEC>
__launch_bounds__(256)
__global__ void k_stats2(const ushort_t* h, const int* batch, float* sums, float* sumsq,
                         int withSq) {
    constexpr int C = VEC * 64;
    int wave = threadIdx.x >> 6, lane = threadIdx.x & 63;
    int n0 = blockIdx.x * 128 + wave * 32;
    if (n0 >= NN) return;
    int n1 = n0 + 32 < NN ? n0 + 32 : NN;
    int coff = lane * VEC;
    float s[VEC], sq[VEC];
#pragma unroll
    for (int i = 0; i < VEC; ++i) { s[i] = 0.f; sq[i] = 0.f; }
    int cur = batch[n0];
    for (int n = n0; n < n1; ++n) {
        int g = batch[n];
        if (g != cur) {
#pragma unroll
            for (int i = 0; i < VEC; ++i) {
                atomicAdd(&sums[cur * C + coff + i], s[i]);
                if (withSq) atomicAdd(&sumsq[cur * C + coff + i], sq[i]);
                s[i] = 0.f; sq[i] = 0.f;
            }
            cur = g;
        }
        __bf16 v[VEC];
        __builtin_memcpy(v, h + (size_t)n * C + coff, VEC * 2);
#pragma unroll
        for (int i = 0; i < VEC; ++i) {
            float f = (float)v[i];
            s[i] += f; sq[i] += f * f;
        }
    }
#pragma unroll
    for (int i = 0; i < VEC; ++i) {
        atomicAdd(&sums[cur * C + coff + i], s[i]);
        if (withSq) atomicAdd(&sumsq[cur * C + coff + i], sq[i]);
    }
}

// ---------- GraphNorm + leaky ReLU (+ residual on last layer), wave-per-node ----
template<int VEC>
__launch_bounds__(256)
__global__ void k_norm2(const ushort_t* hpre, const int* batch, const float* sums,
                        const float* sumsq, const float* cntf,
                        const ushort_t* gw, const ushort_t* gb, const ushort_t* gms,
                        const ushort_t* xres, ushort_t* out, int addres) {
    constexpr int C = VEC * 64;
    int n = blockIdx.x * 4 + (threadIdx.x >> 6);
    if (n >= NN) return;
    int lane = threadIdx.x & 63;
    int coff = lane * VEC;
    int g = batch[n];
    float cg = cntf[g];
    float sm[VEC], sq[VEC];
    __builtin_memcpy(sm, sums  + g * C + coff, VEC * 4);
    __builtin_memcpy(sq, sumsq + g * C + coff, VEC * 4);
    __bf16 vgw[VEC], vgb[VEC], vms[VEC], vh[VEC];
    __builtin_memcpy(vgw, gw + coff, VEC * 2);
    __builtin_memcpy(vgb, gb + coff, VEC * 2);
    __builtin_memcpy(vms, gms + coff, VEC * 2);
    __builtin_memcpy(vh, hpre + (size_t)n * C + coff, VEC * 2);
    __bf16 vx[VEC];
    if (addres) __builtin_memcpy(vx, xres + (size_t)n * 128 + coff, VEC * 2);
    ushort_t o[VEC];
#pragma unroll
    for (int i = 0; i < VEC; ++i) {
        float mean = sm[i] / cg;
        float ms = (float)vms[i];
        float var = sq[i] / cg - mean * mean * ms * (2.0f - ms);
        var = fmaxf(var, 0.0f);
        float y = (float)vgw[i] * ((float)vh[i] - ms * mean) * rsqrtf(var + 1e-5f) + (float)vgb[i];
        y = (y >= 0.0f) ? y : 0.2f * y;
        if (addres) y += (float)vx[i];
        o[i] = f2b(y);
    }
    __builtin_memcpy(out + (size_t)n * C + coff, o, VEC * 2);
}

// ---------- head: out = tanh(pooled/cnt @ W1 + b1) @ W2 + b2 ----------
__global__ void k_head(const float* pooled, const float* cntf,
                       const ushort_t* W1, const ushort_t* b1,
                       const ushort_t* W2, const ushort_t* b2s, void* out,
                       const int* flag) {
    __shared__ float pl[128];
    __shared__ float hid[64];
    int g = blockIdx.x, t = threadIdx.x;   // 64 threads
    float inv = 1.0f / cntf[g];
    for (int k = t; k < 128; k += 64) pl[k] = pooled[g * 128 + k] * inv;
    __syncthreads();
    float a = b2f(b1[t]);
    for (int k = 0; k < 128; ++k) a += pl[k] * b2f(W1[k * 64 + t]);
    hid[t] = tanhf(a);
    __syncthreads();
    if (t < 10) {
        float o = b2f(b2s[t]);
        for (int j = 0; j < 64; ++j) o += hid[j] * b2f(W2[j * 10 + t]);
        if (*flag) ((ushort_t*)out)[g * 10 + t] = f2b(o);
        else       ((float*)out)[g * 10 + t]    = o;
    }
}

extern "C" void kernel_launch(void* const* d_in, const int* in_sizes, int n_in,
                              void* d_out, int out_size, void* d_ws, size_t ws_size,
                              hipStream_t stream) {
    (void)in_sizes; (void)n_in; (void)out_size; (void)ws_size;

    const void* x_raw = d_in[0];
    const int* edge   = (const int*)d_in[1];
    const int* batch  = (const int*)d_in[2];

    // ---- workspace layout (256B-aligned; total 228,991,488 B ≈ 229 MB) ----
    char* ws = (char*)d_ws;
    float*    dinv   = (float*)   (ws + 0);           //   200,000 B
    int*      degi   = (int*)     (ws + 200192);      //   200,000 B
    int*      rowptr = (int*)     (ws + 400384);      //   200,004 B
    int*      cursor = (int*)     (ws + 600576);      //   200,000 B
    int*      bsum   = (int*)     (ws + 800768);      //       196 B
    int*      boff   = (int*)     (ws + 801024);      //       196 B
    float*    cntf   = (float*)   (ws + 801280);      //       200 B
    int*      dflag  = (int*)     (ws + 801488);      //         4 B
    float*    sums   = (float*)   (ws + 801792);      //   102,400 B
    float*    sumsq  = (float*)   (ws + 904192);      //   102,400 B (adjacent)
    float*    pooled = (float*)   (ws + 1006592);     //    25,600 B -> 1,032,192
    ushort_t* Xb     = (ushort_t*)(ws + 1032192);     // 12,800,000 B  x staged bf16
    ushort_t* Wst    = (ushort_t*)(ws + 13832192);    //  1,966,080 B  conv W staged
    ushort_t* WTall  = (ushort_t*)(ws + 15798272);    //  1,966,080 B  conv W packed
    ushort_t* SB     = (ushort_t*)(ws + 17764352);    //     27,028 B  small tensors staged
    int2*     epack  = (int2*)    (ws + 17791488);    //  6,400,000 B  packed CSR (src,w)
    ushort_t* T1     = (ushort_t*)(ws + 24191488);    // 51,200,000 B  (T1+T2 contiguous = G region)
    ushort_t* T2     = (ushort_t*)(ws + 75391488);    // 51,200,000 B
    ushort_t* P      = (ushort_t*)(ws + 126591488);   // 51,200,000 B
    ushort_t* HA     = (ushort_t*)(ws + 177791488);   // 51,200,000 B -> end 228,991,488

    const int cins[4]  = {128, 256, 512, 256};
    const int couts[4] = {256, 512, 256, 128};
    const size_t wtoff[4] = {0, 98304, 491520, 884736};  // elem offsets (Wst & WTall)
    // SB element offsets
    const int bo[4] = {0, 256, 768, 1024};
    const int gwo = 1152, gbo = 2304, gmo = 3456;
    const int l1Wo = 4608, l1bo = 12800, l2Wo = 12864, l2bo = 13504;

    const int XB_E = 1032192 / 2, WST_E = 13832192 / 2, SB_E = 17764352 / 2;

    // ---- batched cast jobs ----
    CastJobs jb;
    int sizes[25]; int nj = 0;
    auto addjob = [&](const void* s, int off, int n) {
        jb.src[nj] = s; jb.off[nj] = off; sizes[nj] = n; ++nj;
    };
    addjob(x_raw, XB_E, NN * 128);
    for (int l = 0; l < 4; ++l) {
        addjob(d_in[3 + 5 * l], WST_E + (int)wtoff[l], 3 * cins[l] * couts[l]);
        addjob(d_in[4 + 5 * l], SB_E + bo[l],        couts[l]);
        addjob(d_in[5 + 5 * l], SB_E + gwo + bo[l],  couts[l]);
        addjob(d_in[6 + 5 * l], SB_E + gbo + bo[l],  couts[l]);
        addjob(d_in[7 + 5 * l], SB_E + gmo + bo[l],  couts[l]);
    }
    addjob(d_in[23], SB_E + l1Wo, 128 * 64);
    addjob(d_in[24], SB_E + l1bo, 64);
    addjob(d_in[25], SB_E + l2Wo, 64 * 10);
    addjob(d_in[26], SB_E + l2bo, 10);
    int run = 0;
    for (int k = 0; k < 25; ++k) { jb.start[k] = run; run += sizes[k]; }
    jb.start[25] = run;

    // ---- batched transpose jobs (8 jobs, 32x32 tiles) ----
    TJobs tj;
    int tn = 0, trun = 0;
    auto addt = [&](int soff, int doff, int K, int C) {
        tj.soff[tn] = soff; tj.doff[tn] = doff; tj.K[tn] = K; tj.C[tn] = C;
        tj.tstart[tn] = trun; trun += (K / 32) * (C / 32); ++tn;
    };
    addt((int)wtoff[0], (int)wtoff[0], 3 * cins[0], couts[0]);           // l0: 384x256
    addt((int)wtoff[1], (int)wtoff[1], 3 * cins[1], couts[1]);           // l1: 768x512
    for (int l = 2; l < 4; ++l)
        for (int j2 = 0; j2 < 3; ++j2) {
            int o = (int)wtoff[l] + j2 * cins[l] * couts[l];
            addt(o, o, cins[l], couts[l]);                               // per-j cinxcout
        }
    tj.tstart[8] = trun;   // 960 tiles

    // dtype detect; castall zeroes degi; scan3 zeroes cursor
    k_detect<<<1, 512, 0, stream>>>((const ushort_t*)x_raw, dflag);
    hipMemsetAsync(pooled, 0, BG * 128 * 4, stream);
    k_castall<<<(run + 255) / 256, 256, 0, stream>>>(jb, (ushort_t*)ws, dflag, run, degi);

    // graph prep
    k_deg<<<(EE + 255) / 256, 256, 0, stream>>>(edge, degi);
    k_scan1<<<49, 1024, 0, stream>>>(degi, rowptr, bsum, dinv);
    k_scan2<<<1, 64, 0, stream>>>(bsum, boff, rowptr, batch, cntf);
    k_scan3<<<(NN + 255) / 256, 256, 0, stream>>>(rowptr, boff, cursor);
    k_fill<<<(EE + 255) / 256, 256, 0, stream>>>(edge, dinv, rowptr, cursor, epack);

    // weight packing (all 8 transposes, one dispatch)
    k_transposeAll<<<trun, dim3(32, 8), 0, stream>>>(tj, Wst, WTall);

    const int NB = (NN + 3) / 4;
    const int SBk = (NN + 127) / 128;
    const int MT = (NN + 127) / 128;          // 391 M-tiles
    const int MG = (MT + 7) / 8;              // 49 groups of 8
    auto prop = [&](int C, ushort_t* o, int ldo,
                    const ushort_t* s, int lds_, int soff,
                    const ushort_t* aP, int lda_, int aoff,
                    const ushort_t* sP, int ldsu, int suoff,
                    const ushort_t* bias, float alpha) {
        if (C == 128)
            k_prop3<16><<<NB, 256, 0, stream>>>(o, ldo, s, lds_, soff, aP, lda_, aoff,
                                                sP, ldsu, suoff, bias, alpha, rowptr, epack);
        else
            k_prop3<32><<<NB, 256, 0, stream>>>(o, ldo, s, lds_, soff, aP, lda_, aoff,
                                                sP, ldsu, suoff, bias, alpha, rowptr, epack);
    };
    auto gemm = [&](const ushort_t* A0, const ushort_t* A1, const ushort_t* A2,
                    int lda, const ushort_t* WT, const ushort_t* bias, int hasBias,
                    ushort_t* o, int ldout, int Ktot, int NX) {
        k_gemm<<<MG * 8 * NX, 256, 0, stream>>>(A0, A1, A2, lda, WT, bias, hasBias,
                                                o, ldout, Ktot, NX, MT);
    };
    auto stats = [&](int C, const ushort_t* h, float* sm, float* sq, int withSq) {
        if (C == 128)      k_stats2<2><<<SBk, 256, 0, stream>>>(h, batch, sm, sq, withSq);
        else if (C == 256) k_stats2<4><<<SBk, 256, 0, stream>>>(h, batch, sm, sq, withSq);
        else               k_stats2<8><<<SBk, 256, 0, stream>>>(h, batch, sm, sq, withSq);
    };
    auto norm = [&](int C, const ushort_t* hp, const ushort_t* gwp, const ushort_t* gbp,
                    const ushort_t* gmp, ushort_t* o, int addres) {
        if (C == 128)      k_norm2<2><<<NB, 256, 0, stream>>>(hp, batch, sums, sumsq, cntf, gwp, gbp, gmp, Xb, o, addres);
        else if (C == 256) k_norm2<4><<<NB, 256, 0, stream>>>(hp, batch, sums, sumsq, cntf, gwp, gbp, gmp, Xb, o, addres);
        else               k_norm2<8><<<NB, 256, 0, stream>>>(hp, batch, sums, sumsq, cntf, gwp, gbp, gmp, Xb, o, addres);
    };

    ushort_t* G = T1;   // mode-B GEMM output (M x 3cout), uses T1+T2 contiguous region
    const ushort_t* hin = Xb;
    for (int l = 0; l < 4; ++l) {
        int cin = cins[l], cout = couts[l];
        if (l < 2) {
            // mode A: propagate in cin, then fat-K GEMM
            prop(cin, T1, cin, hin, cin, 0, nullptr, 0, 0, nullptr, 0, 0, nullptr, 1.0f);
            prop(cin, T2, cin, T1, cin, 0, nullptr, 0, 0, hin, cin, 0, nullptr, 2.0f);
            gemm(hin, T1, T2, cin, WTall + wtoff[l], SB + bo[l], 1, P, cout, 3 * cin,
                 cout / 128);
        } else {
            // mode B: GEMM first (G=[xW0|xW1|xW2]), then propagate in cout
            //   V = G1 + 2*prop(G2);  Ppre = prop(V) + G0 - G2 + bias
            gemm(hin, hin, hin, cin, WTall + wtoff[l], nullptr, 0, G, 3 * cout, cin,
                 (3 * cout) / 128);
            ushort_t* V = HA;   // hin (HA) is dead after the GEMM above
            prop(cout, V, cout, G, 3 * cout, 2 * cout, G, 3 * cout, cout,
                 nullptr, 0, 0, nullptr, 2.0f);
            prop(cout, P, cout, V, cout, 0, G, 3 * cout, 0,
                 G, 3 * cout, 2 * cout, SB + bo[l], 1.0f);
        }
        hipMemsetAsync(sums, 0, 2 * 102400, stream);   // sums + sumsq (adjacent)
        stats(cout, P, sums, sumsq, 1);
        norm(cout, P, SB + gwo + bo[l], SB + gbo + bo[l], SB + gmo + bo[l], HA, l == 3);
        hin = HA;
    }
    // mean-pool (sum; divide in head) + head
    stats(128, HA, pooled, pooled, 0);
    k_head<<<BG, 64, 0, stream>>>(pooled, cntf, SB + l1Wo, SB + l1bo, SB + l2Wo, SB + l2bo,
                                  d_out, dflag);
}